// Round 15
// baseline (314.371 us; speedup 1.0000x reference)
//
#include <hip/hip_runtime.h>
#include <hip/hip_bf16.h>

typedef __attribute__((ext_vector_type(8)))  short  bf16x8;
typedef __attribute__((ext_vector_type(4)))  float  f32x4;
typedef __attribute__((ext_vector_type(16))) float  f32x16;
typedef __attribute__((ext_vector_type(4)))  int    i32x4;
typedef __attribute__((ext_vector_type(4)))  unsigned int u32x4;

#define NH   12
#define NKV  2
#define GRP  6
#define HD   128
#define SEQL 4096
#define QD   (NH*HD)
#define KD   (NKV*HD)
#define NT_KV (SEQL/32)     // 128 kv tiles of 32 rows per head
#define TILE_B 8192         // bytes per 32x128 bf16 tile
#define WS_NEED ((size_t)2 * NKV * NT_KV * TILE_B)   // 4 MB: KW + VW

// SCALE * log2(e): softmax in exp2 domain
static constexpr float SCL = 0.08838834764831845f * 1.44269504088896340736f;

static __device__ __forceinline__ unsigned int f2bf(float x) {
    union { __hip_bfloat16 h; unsigned short u; } cv;
    cv.h = __float2bfloat16(x);
    return (unsigned int)cv.u;
}
static __device__ __forceinline__ unsigned int pk2(float x, float y) {
    return f2bf(x) | (f2bf(y) << 16);
}

// ---- pre-pass: K -> bf16 in QK A-fragment order ----
__global__ __launch_bounds__(256) void conv_k(const float* __restrict__ K,
                                              char* __restrict__ KW) {
    int id = blockIdx.x*256 + threadIdx.x;      // 131072 threads
    int l31  = id & 31;
    int hi   = (id >> 5) & 1;
    int c    = (id >> 6) & 7;
    int tile = (id >> 9) & 127;
    int kvh  = id >> 16;
    const float* src = K + (size_t)(tile*32 + l31)*KD + kvh*HD + c*16 + hi*8;
    const f32x4* s4 = reinterpret_cast<const f32x4*>(src);
    f32x4 a = s4[0], b = s4[1];
    bf16x8 t;
    t[0]=(short)f2bf(a[0]); t[1]=(short)f2bf(a[1]); t[2]=(short)f2bf(a[2]); t[3]=(short)f2bf(a[3]);
    t[4]=(short)f2bf(b[0]); t[5]=(short)f2bf(b[1]); t[6]=(short)f2bf(b[2]); t[7]=(short)f2bf(b[3]);
    *reinterpret_cast<bf16x8*>(KW + (size_t)(kvh*NT_KV + tile)*TILE_B
                               + c*1024 + (hi*32 + l31)*16) = t;
}

// ---- pre-pass: V -> bf16 in 32x32x16 MFMA B-fragment layout ----
__global__ __launch_bounds__(256) void conv_v(const float* __restrict__ V,
                                              char* __restrict__ VW) {
    int id = blockIdx.x*256 + threadIdx.x;      // 131072 threads
    int d    = id & 127;
    int hi   = (id >> 7) & 1;
    int kc   = (id >> 8) & 1;
    int tile = (id >> 9) & 127;
    int kvh  = id >> 16;
    const float* vp = V + (size_t)(tile*32 + kc*16 + hi*8)*KD + kvh*HD + d;
    bf16x8 t;
    #pragma unroll
    for (int j = 0; j < 8; ++j) t[j] = (short)f2bf(vp[(size_t)j*KD]);
    char* dst = VW + (size_t)(kvh*NT_KV + tile)*TILE_B
              + (d>>5)*2048 + kc*1024 + (d&31)*32 + hi*16;
    *reinterpret_cast<bf16x8*>(dst) = t;
}

// ===================== fast path =====================
// Uniform-work paired blocks (R14) + __launch_bounds__(256,3): cap VGPR at
// ~170 so 3 blocks/CU (=12 waves/CU) stay resident for the WHOLE kernel.
// R14 measured: natural alloc 192 -> only 2 blocks/CU resident, occupancy
// 11%. R13's nearly identical body fit 164, so 170 target should squeeze
// without spilling (tripwire: WRITE_SIZE must stay ~24.6 MB).
__global__ __launch_bounds__(256, 3) void gqa_attn_fwd(
        const float* __restrict__ Q,
        const char* __restrict__ KW,
        const char* __restrict__ VW,
        float* __restrict__ O)
{
    __shared__ float bufA[32*128];   // 16 KB merge buffer
    __shared__ float bufB[32*128];   // 16 KB merge buffer
    __shared__ float cmA[64];        // m[32], l[32]
    __shared__ float cmB[64];

    const int tid  = threadIdx.x;
    const int wv   = tid >> 6;       // 0..3
    const int lane = tid & 63;
    const int l31  = lane & 31;
    const int hi   = lane >> 5;

    const int bid = blockIdx.x;      // 768 blocks
    const int h   = bid % NH;
    const int pr  = bid / NH;        // 0..63
    const int kvh = h / GRP;

    const char* kw0 = KW + (size_t)kvh*NT_KV*TILE_B;
    const char* vw0 = VW + (size_t)kvh*NT_KV*TILE_B;
    const int klocal = lane*16;
    const int vlocal = l31*32 + hi*16;

    for (int ph = 0; ph < 2; ++ph) {
        const int qt = (ph == 0) ? pr : (127 - pr);
        const int q0 = qt * 32;

        // ---- Q fragments for this phase's q-tile, prescaled ----
        bf16x8 qf[8];
        {
            const float* qp = Q + (size_t)(q0 + l31)*QD + h*HD + hi*8;
            #pragma unroll
            for (int c = 0; c < 8; ++c) {
                const f32x4* p4 = reinterpret_cast<const f32x4*>(qp + c*16);
                f32x4 a = p4[0], b = p4[1];
                bf16x8 f;
                f[0]=(short)f2bf(a[0]*SCL); f[1]=(short)f2bf(a[1]*SCL);
                f[2]=(short)f2bf(a[2]*SCL); f[3]=(short)f2bf(a[3]*SCL);
                f[4]=(short)f2bf(b[0]*SCL); f[5]=(short)f2bf(b[1]*SCL);
                f[6]=(short)f2bf(b[2]*SCL); f[7]=(short)f2bf(b[3]*SCL);
                qf[c] = f;
            }
        }

        f32x16 oa[4];
        #pragma unroll
        for (int dc = 0; dc < 4; ++dc)
            #pragma unroll
            for (int r = 0; r < 16; ++r) oa[dc][r] = 0.f;
        float m_run = -1e30f, lsum = 0.f;   // per-lane HALF-sum (hi splits kv rows)

        // ---- main loop: single K reg buffer, post-QK prefetch (R13 body) ----
        bf16x8 kf[8];
        {
            const char* kt0 = kw0 + (size_t)wv*TILE_B + klocal;
            #pragma unroll
            for (int c = 0; c < 8; ++c)
                kf[c] = *reinterpret_cast<const bf16x8*>(kt0 + c*1024);
        }

        for (int t = wv; t <= qt; t += 4) {
            // V loads issued first, consumed at PV -> L2 latency hidden
            const char* vt = vw0 + (size_t)t*TILE_B + vlocal;
            bf16x8 vf[8];
            #pragma unroll
            for (int i = 0; i < 8; ++i)
                vf[i] = *reinterpret_cast<const bf16x8*>(vt + (i>>1)*2048 + (i&1)*1024);

            // ---- QK^T: S^T[kv][q], lane = one q column; 2 split chains ----
            f32x16 sA, sB;
            #pragma unroll
            for (int r = 0; r < 16; ++r) { sA[r] = 0.f; sB[r] = 0.f; }
            __builtin_amdgcn_s_setprio(1);
            #pragma unroll
            for (int c = 0; c < 4; ++c) {
                sA = __builtin_amdgcn_mfma_f32_32x32x16_bf16(kf[c],   qf[c],   sA, 0, 0, 0);
                sB = __builtin_amdgcn_mfma_f32_32x32x16_bf16(kf[c+4], qf[c+4], sB, 0, 0, 0);
            }
            __builtin_amdgcn_s_setprio(0);

            // prefetch next K tile into the SAME regs (kf dead after QK issue)
            if (t + 4 <= qt) {
                const char* kt = kw0 + (size_t)(t+4)*TILE_B + klocal;
                #pragma unroll
                for (int c = 0; c < 8; ++c)
                    kf[c] = *reinterpret_cast<const bf16x8*>(kt + c*1024);
            }

            f32x16 s;
            #pragma unroll
            for (int r = 0; r < 16; ++r) s[r] = sA[r] + sB[r];

            // ---- causal mask (diagonal tile only) ----
            if (t == qt) {
                const int qabs = q0 + l31;
                #pragma unroll
                for (int r = 0; r < 16; ++r) {
                    const int kvi = q0 + (r&3) + 8*(r>>2) + 4*hi;
                    if (kvi > qabs) s[r] = -1e30f;
                }
            }

            // ---- online softmax (defer-max, THR=8); max tree ----
            float m0 = fmaxf(fmaxf(s[0],s[1]),  fmaxf(s[2],s[3]));
            float m1 = fmaxf(fmaxf(s[4],s[5]),  fmaxf(s[6],s[7]));
            float m2 = fmaxf(fmaxf(s[8],s[9]),  fmaxf(s[10],s[11]));
            float m3 = fmaxf(fmaxf(s[12],s[13]), fmaxf(s[14],s[15]));
            float pmax = fmaxf(fmaxf(m0,m1), fmaxf(m2,m3));
            pmax = fmaxf(pmax, __shfl_xor(pmax, 32));   // halves agree on m

            if (__ballot(pmax > m_run + 8.0f)) {
                const float mnew  = fmaxf(m_run, pmax);
                const float alpha = exp2f(m_run - mnew);
                m_run = mnew;
                lsum *= alpha;
                #pragma unroll
                for (int r = 0; r < 16; ++r) {
                    const float ar = __shfl(alpha, (r&3) + 8*(r>>2) + 4*hi, 64);
                    #pragma unroll
                    for (int dc = 0; dc < 4; ++dc) oa[dc][r] *= ar;
                }
            }

            float ps0 = 0.f, ps1 = 0.f;
            #pragma unroll
            for (int r = 0; r < 16; r += 2) {
                s[r]   = exp2f(s[r]   - m_run); ps0 += s[r];
                s[r+1] = exp2f(s[r+1] - m_run); ps1 += s[r+1];
            }
            lsum += ps0 + ps1;

            // ---- P -> A-fragment via permlane32_swap ----
            unsigned w0, w1, w2, w3, w4, w5, w6, w7;
            {
                unsigned a = pk2(s[0],  s[1]),  b = pk2(s[4],  s[5]);
                auto r0 = __builtin_amdgcn_permlane32_swap(a, b, false, false);
                w0 = r0[0]; w2 = r0[1];
                unsigned c2 = pk2(s[2],  s[3]),  d2 = pk2(s[6],  s[7]);
                auto r1 = __builtin_amdgcn_permlane32_swap(c2, d2, false, false);
                w1 = r1[0]; w3 = r1[1];
                unsigned e = pk2(s[8],  s[9]),  f = pk2(s[12], s[13]);
                auto r2 = __builtin_amdgcn_permlane32_swap(e, f, false, false);
                w4 = r2[0]; w6 = r2[1];
                unsigned g = pk2(s[10], s[11]), hh = pk2(s[14], s[15]);
                auto r3 = __builtin_amdgcn_permlane32_swap(g, hh, false, false);
                w5 = r3[0]; w7 = r3[1];
            }
            const bf16x8 pa0 = __builtin_bit_cast(bf16x8, (u32x4){w0, w1, w2, w3});
            const bf16x8 pa1 = __builtin_bit_cast(bf16x8, (u32x4){w4, w5, w6, w7});

            // ---- PV ----
            __builtin_amdgcn_s_setprio(1);
            #pragma unroll
            for (int dc = 0; dc < 4; ++dc) {
                oa[dc] = __builtin_amdgcn_mfma_f32_32x32x16_bf16(pa0, vf[dc*2],   oa[dc], 0, 0, 0);
                oa[dc] = __builtin_amdgcn_mfma_f32_32x32x16_bf16(pa1, vf[dc*2+1], oa[dc], 0, 0, 0);
            }
            __builtin_amdgcn_s_setprio(0);
        }

        // ---- combine the two kv-row halves of lsum ----
        lsum += __shfl_xor(lsum, 32);

        // ---- 4-way flash-merge tree for this phase's q-tile ----
        __syncthreads();   // protects buffer reuse across phases
        if (wv == 1) {
            if (hi == 0) { cmA[l31] = m_run; cmA[32 + l31] = lsum; }
            #pragma unroll
            for (int r = 0; r < 16; ++r) {
                const int qr = (r&3) + 8*(r>>2) + 4*hi;
                #pragma unroll
                for (int dc = 0; dc < 4; ++dc) bufA[qr*128 + dc*32 + l31] = oa[dc][r];
            }
        } else if (wv == 3) {
            if (hi == 0) { cmB[l31] = m_run; cmB[32 + l31] = lsum; }
            #pragma unroll
            for (int r = 0; r < 16; ++r) {
                const int qr = (r&3) + 8*(r>>2) + 4*hi;
                #pragma unroll
                for (int dc = 0; dc < 4; ++dc) bufB[qr*128 + dc*32 + l31] = oa[dc][r];
            }
        }
        __syncthreads();
        if (wv == 0 || wv == 2) {
            const float* cb = (wv == 0) ? cmA  : cmB;
            const float* ob = (wv == 0) ? bufA : bufB;
            const float mo = cb[l31], lo2 = cb[32 + l31];
            const float M  = fmaxf(m_run, mo);
            const float a0 = exp2f(m_run - M);
            const float a1 = exp2f(mo - M);
            lsum  = lsum*a0 + lo2*a1;
            m_run = M;
            #pragma unroll
            for (int r = 0; r < 16; ++r) {
                const int qr = (r&3) + 8*(r>>2) + 4*hi;
                const float a0r = __shfl(a0, qr, 64);
                const float a1r = __shfl(a1, qr, 64);
                #pragma unroll
                for (int dc = 0; dc < 4; ++dc)
                    oa[dc][r] = oa[dc][r]*a0r + ob[qr*128 + dc*32 + l31]*a1r;
            }
        }
        __syncthreads();   // w0 done reading bufA before w2 overwrites it
        if (wv == 2) {
            if (hi == 0) { cmA[l31] = m_run; cmA[32 + l31] = lsum; }
            #pragma unroll
            for (int r = 0; r < 16; ++r) {
                const int qr = (r&3) + 8*(r>>2) + 4*hi;
                #pragma unroll
                for (int dc = 0; dc < 4; ++dc) bufA[qr*128 + dc*32 + l31] = oa[dc][r];
            }
        }
        __syncthreads();
        if (wv == 0) {
            const float mo = cmA[l31], lo2 = cmA[32 + l31];
            const float M  = fmaxf(m_run, mo);
            const float a0 = exp2f(m_run - M);
            const float a1 = exp2f(mo - M);
            const float inv = 1.0f / (lsum*a0 + lo2*a1);
            #pragma unroll
            for (int r = 0; r < 16; ++r) {
                const int qr = (r&3) + 8*(r>>2) + 4*hi;
                const float a0r = __shfl(a0, qr, 64);
                const float a1r = __shfl(a1, qr, 64);
                const float ivr = __shfl(inv, qr, 64);
                float* op = O + (size_t)(q0 + qr)*QD + h*HD + l31;
                #pragma unroll
                for (int dc = 0; dc < 4; ++dc) {
                    const float merged = oa[dc][r]*a0r + bufA[qr*128 + dc*32 + l31]*a1r;
                    op[dc*32] = merged * ivr;
                }
            }
        }
    }
}

// ===================== fallback: self-staging (no workspace), verified R1 =====================
__global__ __launch_bounds__(256) void gqa_attn_fwd_fb(
        const float* __restrict__ Q, const float* __restrict__ K,
        const float* __restrict__ V, float* __restrict__ O)
{
    __shared__ unsigned short K_lds[32*128];
    __shared__ unsigned short V_lds[32*128];

    const int tid  = threadIdx.x;
    const int wv   = tid >> 6;
    const int lane = tid & 63;
    const int lo   = lane & 15;
    const int g    = lane >> 4;

    const int bid = blockIdx.x;
    const int h   = bid % NH;
    const int qt  = (SEQL/64 - 1) - bid / NH;
    const int q0  = qt * 64;
    const int kvh = h / GRP;

    bf16x8 qf[4];
    {
        const int qrow = q0 + wv*16 + lo;
        const float* qp = Q + (size_t)qrow*QD + h*HD + g*8;
        #pragma unroll
        for (int c = 0; c < 4; ++c) {
            const f32x4* p = reinterpret_cast<const f32x4*>(qp + c*32);
            f32x4 a = p[0], b = p[1];
            bf16x8 f;
            f[0]=(short)f2bf(a[0]*SCL); f[1]=(short)f2bf(a[1]*SCL);
            f[2]=(short)f2bf(a[2]*SCL); f[3]=(short)f2bf(a[3]*SCL);
            f[4]=(short)f2bf(b[0]*SCL); f[5]=(short)f2bf(b[1]*SCL);
            f[6]=(short)f2bf(b[2]*SCL); f[7]=(short)f2bf(b[3]*SCL);
            qf[c] = f;
        }
    }

    f32x4 oa[8];
    #pragma unroll
    for (int i = 0; i < 8; ++i) oa[i] = (f32x4){0.f, 0.f, 0.f, 0.f};
    float m_run = -1e30f, lsum = 0.f;

    const int qmax_w = q0 + wv*16 + 15;
    const int nt = q0/32 + 2;

    for (int t = 0; t < nt; ++t) {
        const int kvb = t*32;
        __syncthreads();
        {
            const int row = tid >> 3;
            const int dc  = (tid & 7) * 16;
            const float* kp = K + (size_t)(kvb+row)*KD + kvh*HD + dc;
            const f32x4* kp4 = reinterpret_cast<const f32x4*>(kp);
            f32x4 a0 = kp4[0], a1 = kp4[1], a2 = kp4[2], a3 = kp4[3];
            bf16x8 t0, t1;
            t0[0]=(short)f2bf(a0[0]); t0[1]=(short)f2bf(a0[1]); t0[2]=(short)f2bf(a0[2]); t0[3]=(short)f2bf(a0[3]);
            t0[4]=(short)f2bf(a1[0]); t0[5]=(short)f2bf(a1[1]); t0[6]=(short)f2bf(a1[2]); t0[7]=(short)f2bf(a1[3]);
            t1[0]=(short)f2bf(a2[0]); t1[1]=(short)f2bf(a2[1]); t1[2]=(short)f2bf(a2[2]); t1[3]=(short)f2bf(a2[3]);
            t1[4]=(short)f2bf(a3[0]); t1[5]=(short)f2bf(a3[1]); t1[6]=(short)f2bf(a3[2]); t1[7]=(short)f2bf(a3[3]);
            char* kl = reinterpret_cast<char*>(K_lds);
            const int byte = row*256 + dc*2;
            const int swzw = (row & 7) << 4;
            *reinterpret_cast<bf16x8*>(kl + ((byte)      ^ swzw)) = t0;
            *reinterpret_cast<bf16x8*>(kl + ((byte + 16) ^ swzw)) = t1;
        }
        {
            const int kv0   = (tid >> 4) * 2;
            const int dbase = (tid & 15) * 8;
            const float* vp = V + (size_t)(kvb+kv0)*KD + kvh*HD + dbase;
            const f32x4* v0 = reinterpret_cast<const f32x4*>(vp);
            const f32x4* v1 = reinterpret_cast<const f32x4*>(vp + KD);
            f32x4 a0 = v0[0], a1 = v0[1], b0 = v1[0], b1 = v1[1];
            unsigned int* vf = reinterpret_cast<unsigned int*>(V_lds);
            #pragma unroll
            for (int i = 0; i < 8; ++i) {
                float x0 = (i < 4) ? a0[i] : a1[i-4];
                float x1 = (i < 4) ? b0[i] : b1[i-4];
                unsigned int pkv = f2bf(x0) | (f2bf(x1) << 16);
                const int d  = dbase + i;
                const int db = d >> 4, dl = d & 15;
                const int slot = (kv0 >> 3) ^ (d & 3) ^ (db & 3);
                const int byte = db*1024 + dl*64 + slot*16 + (kv0 & 7)*2;
                vf[byte >> 2] = pkv;
            }
        }
        __syncthreads();

        if (kvb > qmax_w) continue;

        f32x4 s0 = {0,0,0,0}, s1 = {0,0,0,0};
        {
            const char* kl = reinterpret_cast<const char*>(K_lds);
            const int r0 = lo, r1 = lo + 16;
            const int sw0 = (r0 & 7) << 4, sw1 = (r1 & 7) << 4;
            #pragma unroll
            for (int c = 0; c < 4; ++c) {
                bf16x8 ka = *reinterpret_cast<const bf16x8*>(kl + ((r0*256 + c*64 + g*16) ^ sw0));
                bf16x8 kb = *reinterpret_cast<const bf16x8*>(kl + ((r1*256 + c*64 + g*16) ^ sw1));
                s0 = __builtin_amdgcn_mfma_f32_16x16x32_bf16(ka, qf[c], s0, 0, 0, 0);
                s1 = __builtin_amdgcn_mfma_f32_16x16x32_bf16(kb, qf[c], s1, 0, 0, 0);
            }
        }

        const int qabs = q0 + wv*16 + lo;
        if (kvb + 31 > q0 + wv*16) {
            #pragma unroll
            for (int r = 0; r < 4; ++r) {
                if (kvb + 4*g + r      > qabs) s0[r] = -1e30f;
                if (kvb + 16 + 4*g + r > qabs) s1[r] = -1e30f;
            }
        }

        float pmax = fmaxf(fmaxf(fmaxf(s0[0],s0[1]), fmaxf(s0[2],s0[3])),
                           fmaxf(fmaxf(s1[0],s1[1]), fmaxf(s1[2],s1[3])));
        pmax = fmaxf(pmax, __shfl_xor(pmax, 16));
        pmax = fmaxf(pmax, __shfl_xor(pmax, 32));
        const float m_new = fmaxf(m_run, pmax);
        const float alpha = exp2f(m_run - m_new);
        float p0[4], p1[4];
        float psum = 0.f;
        #pragma unroll
        for (int r = 0; r < 4; ++r) {
            p0[r] = exp2f(s0[r] - m_new); psum += p0[r];
            p1[r] = exp2f(s1[r] - m_new); psum += p1[r];
        }
        psum += __shfl_xor(psum, 16);
        psum += __shfl_xor(psum, 32);
        lsum = lsum * alpha + psum;
        m_run = m_new;

        unsigned int pk0[2], pk1[2];
        pk0[0] = f2bf(p0[0]) | (f2bf(p0[1]) << 16);
        pk0[1] = f2bf(p0[2]) | (f2bf(p0[3]) << 16);
        pk1[0] = f2bf(p1[0]) | (f2bf(p1[1]) << 16);
        pk1[1] = f2bf(p1[2]) | (f2bf(p1[3]) << 16);

        i32x4 pav;
        #pragma unroll
        for (int pp = 0; pp < 4; ++pp) {
            const int src = lo + ((2*g + (pp >> 1)) & 3) * 16;
            const int v0s = __shfl((int)pk0[pp & 1], src, 64);
            const int v1s = __shfl((int)pk1[pp & 1], src, 64);
            pav[pp] = (g < 2) ? v0s : v1s;
        }
        const bf16x8 paf = __builtin_bit_cast(bf16x8, pav);

        float al[4];
        #pragma unroll
        for (int r = 0; r < 4; ++r) al[r] = __shfl(alpha, 4*g + r, 64);
        #pragma unroll
        for (int db = 0; db < 8; ++db) {
            oa[db][0] *= al[0]; oa[db][1] *= al[1];
            oa[db][2] *= al[2]; oa[db][3] *= al[3];
        }

        const char* vl = reinterpret_cast<const char*>(V_lds);
        #pragma unroll
        for (int db = 0; db < 8; ++db) {
            const int slot = g ^ (lo & 3) ^ (db & 3);
            bf16x8 vfr = *reinterpret_cast<const bf16x8*>(vl + db*1024 + lo*64 + slot*16);
            oa[db] = __builtin_amdgcn_mfma_f32_16x16x32_bf16(paf, vfr, oa[db], 0, 0, 0);
        }
    }

    float li[4];
    #pragma unroll
    for (int r = 0; r < 4; ++r) li[r] = 1.0f / __shfl(lsum, 4*g + r, 64);
    #pragma unroll
    for (int db = 0; db < 8; ++db) {
        #pragma unroll
        for (int r = 0; r < 4; ++r) {
            O[(size_t)(q0 + wv*16 + 4*g + r)*QD + h*HD + db*16 + lo] = oa[db][r] * li[r];
        }
    }
}

extern "C" void kernel_launch(void* const* d_in, const int* in_sizes, int n_in,
                              void* d_out, int out_size, void* d_ws, size_t ws_size,
                              hipStream_t stream) {
    const float* q = (const float*)d_in[0];
    const float* k = (const float*)d_in[1];
    const float* v = (const float*)d_in[2];
    float* out = (float*)d_out;
    (void)in_sizes; (void)n_in; (void)out_size;

    if (ws_size >= WS_NEED && d_ws != nullptr) {
        char* kw = (char*)d_ws;
        char* vw = kw + (size_t)NKV * NT_KV * TILE_B;
        conv_k<<<dim3(512), dim3(256), 0, stream>>>(k, kw);
        conv_v<<<dim3(512), dim3(256), 0, stream>>>(v, vw);
        gqa_attn_fwd<<<dim3(64 * NH), dim3(256), 0, stream>>>(q, kw, vw, out);
    } else {
        gqa_attn_fwd_fb<<<dim3((SEQL/64)*NH), dim3(256), 0, stream>>>(q, k, v, out);
    }
}

// Round 16
// 145.778 us; speedup vs baseline: 2.1565x; 2.1565x over previous
//
#include <hip/hip_runtime.h>
#include <hip/hip_bf16.h>

typedef __attribute__((ext_vector_type(8)))  short  bf16x8;
typedef __attribute__((ext_vector_type(4)))  float  f32x4;
typedef __attribute__((ext_vector_type(16))) float  f32x16;
typedef __attribute__((ext_vector_type(4)))  int    i32x4;
typedef __attribute__((ext_vector_type(4)))  unsigned int u32x4;

#define NH   12
#define NKV  2
#define GRP  6
#define HD   128
#define SEQL 4096
#define QD   (NH*HD)
#define KD   (NKV*HD)
#define NT_KV (SEQL/32)     // 128 kv tiles of 32 rows per head
#define TILE_B 8192         // bytes per 32x128 bf16 tile
#define WS_NEED ((size_t)2 * NKV * NT_KV * TILE_B)   // 4 MB: KW + VW

// SCALE * log2(e): softmax in exp2 domain
static constexpr float SCL = 0.08838834764831845f * 1.44269504088896340736f;

static __device__ __forceinline__ unsigned int f2bf(float x) {
    union { __hip_bfloat16 h; unsigned short u; } cv;
    cv.h = __float2bfloat16(x);
    return (unsigned int)cv.u;
}
static __device__ __forceinline__ unsigned int pk2(float x, float y) {
    return f2bf(x) | (f2bf(y) << 16);
}

// ---- pre-pass: K -> bf16 in QK A-fragment order ----
__global__ __launch_bounds__(256) void conv_k(const float* __restrict__ K,
                                              char* __restrict__ KW) {
    int id = blockIdx.x*256 + threadIdx.x;      // 131072 threads
    int l31  = id & 31;
    int hi   = (id >> 5) & 1;
    int c    = (id >> 6) & 7;
    int tile = (id >> 9) & 127;
    int kvh  = id >> 16;
    const float* src = K + (size_t)(tile*32 + l31)*KD + kvh*HD + c*16 + hi*8;
    const f32x4* s4 = reinterpret_cast<const f32x4*>(src);
    f32x4 a = s4[0], b = s4[1];
    bf16x8 t;
    t[0]=(short)f2bf(a[0]); t[1]=(short)f2bf(a[1]); t[2]=(short)f2bf(a[2]); t[3]=(short)f2bf(a[3]);
    t[4]=(short)f2bf(b[0]); t[5]=(short)f2bf(b[1]); t[6]=(short)f2bf(b[2]); t[7]=(short)f2bf(b[3]);
    *reinterpret_cast<bf16x8*>(KW + (size_t)(kvh*NT_KV + tile)*TILE_B
                               + c*1024 + (hi*32 + l31)*16) = t;
}

// ---- pre-pass: V -> bf16 in 32x32x16 MFMA B-fragment layout ----
__global__ __launch_bounds__(256) void conv_v(const float* __restrict__ V,
                                              char* __restrict__ VW) {
    int id = blockIdx.x*256 + threadIdx.x;      // 131072 threads
    int d    = id & 127;
    int hi   = (id >> 7) & 1;
    int kc   = (id >> 8) & 1;
    int tile = (id >> 9) & 127;
    int kvh  = id >> 16;
    const float* vp = V + (size_t)(tile*32 + kc*16 + hi*8)*KD + kvh*HD + d;
    bf16x8 t;
    #pragma unroll
    for (int j = 0; j < 8; ++j) t[j] = (short)f2bf(vp[(size_t)j*KD]);
    char* dst = VW + (size_t)(kvh*NT_KV + tile)*TILE_B
              + (d>>5)*2048 + kc*1024 + (d&31)*32 + hi*16;
    *reinterpret_cast<bf16x8*>(dst) = t;
}

// ===================== fast path =====================
// R14 body (uniform-work paired q-tiles, natural VGPR=192) + T1 XCD-aware
// block mapping: xcd = bid&7 (round-robin dispatch assumption), kvh = xcd>>2
// -> each XCD touches ONE kv head (2 MB KV working set fits its 4 MB L2
// even with Q streaming). R15 lesson: NEVER force min-waves (live set is
// ~192 VGPR; forcing -> catastrophic spill). Perf-only heuristic: wrong
// dispatch mapping costs speed, not correctness.
__global__ __launch_bounds__(256) void gqa_attn_fwd(
        const float* __restrict__ Q,
        const char* __restrict__ KW,
        const char* __restrict__ VW,
        float* __restrict__ O)
{
    __shared__ float bufA[32*128];   // 16 KB merge buffer
    __shared__ float bufB[32*128];   // 16 KB merge buffer
    __shared__ float cmA[64];        // m[32], l[32]
    __shared__ float cmB[64];

    const int tid  = threadIdx.x;
    const int wv   = tid >> 6;       // 0..3
    const int lane = tid & 63;
    const int l31  = lane & 31;
    const int hi   = lane >> 5;

    // ---- XCD-aware decode: 768 blocks; xcd=bid&7 -> kvh = xcd>>2 ----
    const int bid = blockIdx.x;
    const int xcd = bid & 7;
    const int i8  = bid >> 3;              // 0..95 (per-XCD block index)
    const int kvh = xcd >> 2;              // XCDs 0-3 -> kvh 0; 4-7 -> kvh 1
    const int j   = (xcd & 3)*96 + i8;     // 0..383 within this kvh
    const int h   = kvh*GRP + (j % GRP);
    const int pr  = j / GRP;               // 0..63 (pair index)

    const char* kw0 = KW + (size_t)kvh*NT_KV*TILE_B;
    const char* vw0 = VW + (size_t)kvh*NT_KV*TILE_B;
    const int klocal = lane*16;
    const int vlocal = l31*32 + hi*16;

    for (int ph = 0; ph < 2; ++ph) {
        const int qt = (ph == 0) ? pr : (127 - pr);
        const int q0 = qt * 32;

        // ---- Q fragments for this phase's q-tile, prescaled ----
        bf16x8 qf[8];
        {
            const float* qp = Q + (size_t)(q0 + l31)*QD + h*HD + hi*8;
            #pragma unroll
            for (int c = 0; c < 8; ++c) {
                const f32x4* p4 = reinterpret_cast<const f32x4*>(qp + c*16);
                f32x4 a = p4[0], b = p4[1];
                bf16x8 f;
                f[0]=(short)f2bf(a[0]*SCL); f[1]=(short)f2bf(a[1]*SCL);
                f[2]=(short)f2bf(a[2]*SCL); f[3]=(short)f2bf(a[3]*SCL);
                f[4]=(short)f2bf(b[0]*SCL); f[5]=(short)f2bf(b[1]*SCL);
                f[6]=(short)f2bf(b[2]*SCL); f[7]=(short)f2bf(b[3]*SCL);
                qf[c] = f;
            }
        }

        f32x16 oa[4];
        #pragma unroll
        for (int dc = 0; dc < 4; ++dc)
            #pragma unroll
            for (int r = 0; r < 16; ++r) oa[dc][r] = 0.f;
        float m_run = -1e30f, lsum = 0.f;   // per-lane HALF-sum (hi splits kv rows)

        // ---- main loop: single K reg buffer, post-QK prefetch ----
        bf16x8 kf[8];
        {
            const char* kt0 = kw0 + (size_t)wv*TILE_B + klocal;
            #pragma unroll
            for (int c = 0; c < 8; ++c)
                kf[c] = *reinterpret_cast<const bf16x8*>(kt0 + c*1024);
        }

        for (int t = wv; t <= qt; t += 4) {
            // V loads issued first, consumed at PV -> latency hidden
            const char* vt = vw0 + (size_t)t*TILE_B + vlocal;
            bf16x8 vf[8];
            #pragma unroll
            for (int i = 0; i < 8; ++i)
                vf[i] = *reinterpret_cast<const bf16x8*>(vt + (i>>1)*2048 + (i&1)*1024);

            // ---- QK^T: S^T[kv][q], lane = one q column; 2 split chains ----
            f32x16 sA, sB;
            #pragma unroll
            for (int r = 0; r < 16; ++r) { sA[r] = 0.f; sB[r] = 0.f; }
            __builtin_amdgcn_s_setprio(1);
            #pragma unroll
            for (int c = 0; c < 4; ++c) {
                sA = __builtin_amdgcn_mfma_f32_32x32x16_bf16(kf[c],   qf[c],   sA, 0, 0, 0);
                sB = __builtin_amdgcn_mfma_f32_32x32x16_bf16(kf[c+4], qf[c+4], sB, 0, 0, 0);
            }
            __builtin_amdgcn_s_setprio(0);

            // prefetch next K tile into the SAME regs (kf dead after QK issue)
            if (t + 4 <= qt) {
                const char* kt = kw0 + (size_t)(t+4)*TILE_B + klocal;
                #pragma unroll
                for (int c = 0; c < 8; ++c)
                    kf[c] = *reinterpret_cast<const bf16x8*>(kt + c*1024);
            }

            f32x16 s;
            #pragma unroll
            for (int r = 0; r < 16; ++r) s[r] = sA[r] + sB[r];

            // ---- causal mask (diagonal tile only) ----
            if (t == qt) {
                const int qabs = q0 + l31;
                #pragma unroll
                for (int r = 0; r < 16; ++r) {
                    const int kvi = q0 + (r&3) + 8*(r>>2) + 4*hi;
                    if (kvi > qabs) s[r] = -1e30f;
                }
            }

            // ---- online softmax (defer-max, THR=8); max tree ----
            float m0 = fmaxf(fmaxf(s[0],s[1]),  fmaxf(s[2],s[3]));
            float m1 = fmaxf(fmaxf(s[4],s[5]),  fmaxf(s[6],s[7]));
            float m2 = fmaxf(fmaxf(s[8],s[9]),  fmaxf(s[10],s[11]));
            float m3 = fmaxf(fmaxf(s[12],s[13]), fmaxf(s[14],s[15]));
            float pmax = fmaxf(fmaxf(m0,m1), fmaxf(m2,m3));
            pmax = fmaxf(pmax, __shfl_xor(pmax, 32));   // halves agree on m

            if (__ballot(pmax > m_run + 8.0f)) {
                const float mnew  = fmaxf(m_run, pmax);
                const float alpha = exp2f(m_run - mnew);
                m_run = mnew;
                lsum *= alpha;
                #pragma unroll
                for (int r = 0; r < 16; ++r) {
                    const float ar = __shfl(alpha, (r&3) + 8*(r>>2) + 4*hi, 64);
                    #pragma unroll
                    for (int dc = 0; dc < 4; ++dc) oa[dc][r] *= ar;
                }
            }

            float ps0 = 0.f, ps1 = 0.f;
            #pragma unroll
            for (int r = 0; r < 16; r += 2) {
                s[r]   = exp2f(s[r]   - m_run); ps0 += s[r];
                s[r+1] = exp2f(s[r+1] - m_run); ps1 += s[r+1];
            }
            lsum += ps0 + ps1;

            // ---- P -> A-fragment via permlane32_swap ----
            unsigned w0, w1, w2, w3, w4, w5, w6, w7;
            {
                unsigned a = pk2(s[0],  s[1]),  b = pk2(s[4],  s[5]);
                auto r0 = __builtin_amdgcn_permlane32_swap(a, b, false, false);
                w0 = r0[0]; w2 = r0[1];
                unsigned c2 = pk2(s[2],  s[3]),  d2 = pk2(s[6],  s[7]);
                auto r1 = __builtin_amdgcn_permlane32_swap(c2, d2, false, false);
                w1 = r1[0]; w3 = r1[1];
                unsigned e = pk2(s[8],  s[9]),  f = pk2(s[12], s[13]);
                auto r2 = __builtin_amdgcn_permlane32_swap(e, f, false, false);
                w4 = r2[0]; w6 = r2[1];
                unsigned g = pk2(s[10], s[11]), hh = pk2(s[14], s[15]);
                auto r3 = __builtin_amdgcn_permlane32_swap(g, hh, false, false);
                w5 = r3[0]; w7 = r3[1];
            }
            const bf16x8 pa0 = __builtin_bit_cast(bf16x8, (u32x4){w0, w1, w2, w3});
            const bf16x8 pa1 = __builtin_bit_cast(bf16x8, (u32x4){w4, w5, w6, w7});

            // ---- PV ----
            __builtin_amdgcn_s_setprio(1);
            #pragma unroll
            for (int dc = 0; dc < 4; ++dc) {
                oa[dc] = __builtin_amdgcn_mfma_f32_32x32x16_bf16(pa0, vf[dc*2],   oa[dc], 0, 0, 0);
                oa[dc] = __builtin_amdgcn_mfma_f32_32x32x16_bf16(pa1, vf[dc*2+1], oa[dc], 0, 0, 0);
            }
            __builtin_amdgcn_s_setprio(0);
        }

        // ---- combine the two kv-row halves of lsum ----
        lsum += __shfl_xor(lsum, 32);

        // ---- 4-way flash-merge tree for this phase's q-tile ----
        __syncthreads();   // protects buffer reuse across phases
        if (wv == 1) {
            if (hi == 0) { cmA[l31] = m_run; cmA[32 + l31] = lsum; }
            #pragma unroll
            for (int r = 0; r < 16; ++r) {
                const int qr = (r&3) + 8*(r>>2) + 4*hi;
                #pragma unroll
                for (int dc = 0; dc < 4; ++dc) bufA[qr*128 + dc*32 + l31] = oa[dc][r];
            }
        } else if (wv == 3) {
            if (hi == 0) { cmB[l31] = m_run; cmB[32 + l31] = lsum; }
            #pragma unroll
            for (int r = 0; r < 16; ++r) {
                const int qr = (r&3) + 8*(r>>2) + 4*hi;
                #pragma unroll
                for (int dc = 0; dc < 4; ++dc) bufB[qr*128 + dc*32 + l31] = oa[dc][r];
            }
        }
        __syncthreads();
        if (wv == 0 || wv == 2) {
            const float* cb = (wv == 0) ? cmA  : cmB;
            const float* ob = (wv == 0) ? bufA : bufB;
            const float mo = cb[l31], lo2 = cb[32 + l31];
            const float M  = fmaxf(m_run, mo);
            const float a0 = exp2f(m_run - M);
            const float a1 = exp2f(mo - M);
            lsum  = lsum*a0 + lo2*a1;
            m_run = M;
            #pragma unroll
            for (int r = 0; r < 16; ++r) {
                const int qr = (r&3) + 8*(r>>2) + 4*hi;
                const float a0r = __shfl(a0, qr, 64);
                const float a1r = __shfl(a1, qr, 64);
                #pragma unroll
                for (int dc = 0; dc < 4; ++dc)
                    oa[dc][r] = oa[dc][r]*a0r + ob[qr*128 + dc*32 + l31]*a1r;
            }
        }
        __syncthreads();   // w0 done reading bufA before w2 overwrites it
        if (wv == 2) {
            if (hi == 0) { cmA[l31] = m_run; cmA[32 + l31] = lsum; }
            #pragma unroll
            for (int r = 0; r < 16; ++r) {
                const int qr = (r&3) + 8*(r>>2) + 4*hi;
                #pragma unroll
                for (int dc = 0; dc < 4; ++dc) bufA[qr*128 + dc*32 + l31] = oa[dc][r];
            }
        }
        __syncthreads();
        if (wv == 0) {
            const float mo = cmA[l31], lo2 = cmA[32 + l31];
            const float M  = fmaxf(m_run, mo);
            const float a0 = exp2f(m_run - M);
            const float a1 = exp2f(mo - M);
            const float inv = 1.0f / (lsum*a0 + lo2*a1);
            #pragma unroll
            for (int r = 0; r < 16; ++r) {
                const int qr = (r&3) + 8*(r>>2) + 4*hi;
                const float a0r = __shfl(a0, qr, 64);
                const float a1r = __shfl(a1, qr, 64);
                const float ivr = __shfl(inv, qr, 64);
                float* op = O + (size_t)(q0 + qr)*QD + h*HD + l31;
                #pragma unroll
                for (int dc = 0; dc < 4; ++dc) {
                    const float merged = oa[dc][r]*a0r + bufA[qr*128 + dc*32 + l31]*a1r;
                    op[dc*32] = merged * ivr;
                }
            }
        }
    }
}

// ===================== fallback: self-staging (no workspace), verified R1 =====================
__global__ __launch_bounds__(256) void gqa_attn_fwd_fb(
        const float* __restrict__ Q, const float* __restrict__ K,
        const float* __restrict__ V, float* __restrict__ O)
{
    __shared__ unsigned short K_lds[32*128];
    __shared__ unsigned short V_lds[32*128];

    const int tid  = threadIdx.x;
    const int wv   = tid >> 6;
    const int lane = tid & 63;
    const int lo   = lane & 15;
    const int g    = lane >> 4;

    const int bid = blockIdx.x;
    const int h   = bid % NH;
    const int qt  = (SEQL/64 - 1) - bid / NH;
    const int q0  = qt * 64;
    const int kvh = h / GRP;

    bf16x8 qf[4];
    {
        const int qrow = q0 + wv*16 + lo;
        const float* qp = Q + (size_t)qrow*QD + h*HD + g*8;
        #pragma unroll
        for (int c = 0; c < 4; ++c) {
            const f32x4* p = reinterpret_cast<const f32x4*>(qp + c*32);
            f32x4 a = p[0], b = p[1];
            bf16x8 f;
            f[0]=(short)f2bf(a[0]*SCL); f[1]=(short)f2bf(a[1]*SCL);
            f[2]=(short)f2bf(a[2]*SCL); f[3]=(short)f2bf(a[3]*SCL);
            f[4]=(short)f2bf(b[0]*SCL); f[5]=(short)f2bf(b[1]*SCL);
            f[6]=(short)f2bf(b[2]*SCL); f[7]=(short)f2bf(b[3]*SCL);
            qf[c] = f;
        }
    }

    f32x4 oa[8];
    #pragma unroll
    for (int i = 0; i < 8; ++i) oa[i] = (f32x4){0.f, 0.f, 0.f, 0.f};
    float m_run = -1e30f, lsum = 0.f;

    const int qmax_w = q0 + wv*16 + 15;
    const int nt = q0/32 + 2;

    for (int t = 0; t < nt; ++t) {
        const int kvb = t*32;
        __syncthreads();
        {
            const int row = tid >> 3;
            const int dc  = (tid & 7) * 16;
            const float* kp = K + (size_t)(kvb+row)*KD + kvh*HD + dc;
            const f32x4* kp4 = reinterpret_cast<const f32x4*>(kp);
            f32x4 a0 = kp4[0], a1 = kp4[1], a2 = kp4[2], a3 = kp4[3];
            bf16x8 t0, t1;
            t0[0]=(short)f2bf(a0[0]); t0[1]=(short)f2bf(a0[1]); t0[2]=(short)f2bf(a0[2]); t0[3]=(short)f2bf(a0[3]);
            t0[4]=(short)f2bf(a1[0]); t0[5]=(short)f2bf(a1[1]); t0[6]=(short)f2bf(a1[2]); t0[7]=(short)f2bf(a1[3]);
            t1[0]=(short)f2bf(a2[0]); t1[1]=(short)f2bf(a2[1]); t1[2]=(short)f2bf(a2[2]); t1[3]=(short)f2bf(a2[3]);
            t1[4]=(short)f2bf(a3[0]); t1[5]=(short)f2bf(a3[1]); t1[6]=(short)f2bf(a3[2]); t1[7]=(short)f2bf(a3[3]);
            char* kl = reinterpret_cast<char*>(K_lds);
            const int byte = row*256 + dc*2;
            const int swzw = (row & 7) << 4;
            *reinterpret_cast<bf16x8*>(kl + ((byte)      ^ swzw)) = t0;
            *reinterpret_cast<bf16x8*>(kl + ((byte + 16) ^ swzw)) = t1;
        }
        {
            const int kv0   = (tid >> 4) * 2;
            const int dbase = (tid & 15) * 8;
            const float* vp = V + (size_t)(kvb+kv0)*KD + kvh*HD + dbase;
            const f32x4* v0 = reinterpret_cast<const f32x4*>(vp);
            const f32x4* v1 = reinterpret_cast<const f32x4*>(vp + KD);
            f32x4 a0 = v0[0], a1 = v0[1], b0 = v1[0], b1 = v1[1];
            unsigned int* vf = reinterpret_cast<unsigned int*>(V_lds);
            #pragma unroll
            for (int i = 0; i < 8; ++i) {
                float x0 = (i < 4) ? a0[i] : a1[i-4];
                float x1 = (i < 4) ? b0[i] : b1[i-4];
                unsigned int pkv = f2bf(x0) | (f2bf(x1) << 16);
                const int d  = dbase + i;
                const int db = d >> 4, dl = d & 15;
                const int slot = (kv0 >> 3) ^ (d & 3) ^ (db & 3);
                const int byte = db*1024 + dl*64 + slot*16 + (kv0 & 7)*2;
                vf[byte >> 2] = pkv;
            }
        }
        __syncthreads();

        if (kvb > qmax_w) continue;

        f32x4 s0 = {0,0,0,0}, s1 = {0,0,0,0};
        {
            const char* kl = reinterpret_cast<const char*>(K_lds);
            const int r0 = lo, r1 = lo + 16;
            const int sw0 = (r0 & 7) << 4, sw1 = (r1 & 7) << 4;
            #pragma unroll
            for (int c = 0; c < 4; ++c) {
                bf16x8 ka = *reinterpret_cast<const bf16x8*>(kl + ((r0*256 + c*64 + g*16) ^ sw0));
                bf16x8 kb = *reinterpret_cast<const bf16x8*>(kl + ((r1*256 + c*64 + g*16) ^ sw1));
                s0 = __builtin_amdgcn_mfma_f32_16x16x32_bf16(ka, qf[c], s0, 0, 0, 0);
                s1 = __builtin_amdgcn_mfma_f32_16x16x32_bf16(kb, qf[c], s1, 0, 0, 0);
            }
        }

        const int qabs = q0 + wv*16 + lo;
        if (kvb + 31 > q0 + wv*16) {
            #pragma unroll
            for (int r = 0; r < 4; ++r) {
                if (kvb + 4*g + r      > qabs) s0[r] = -1e30f;
                if (kvb + 16 + 4*g + r > qabs) s1[r] = -1e30f;
            }
        }

        float pmax = fmaxf(fmaxf(fmaxf(s0[0],s0[1]), fmaxf(s0[2],s0[3])),
                           fmaxf(fmaxf(s1[0],s1[1]), fmaxf(s1[2],s1[3])));
        pmax = fmaxf(pmax, __shfl_xor(pmax, 16));
        pmax = fmaxf(pmax, __shfl_xor(pmax, 32));
        const float m_new = fmaxf(m_run, pmax);
        const float alpha = exp2f(m_run - m_new);
        float p0[4], p1[4];
        float psum = 0.f;
        #pragma unroll
        for (int r = 0; r < 4; ++r) {
            p0[r] = exp2f(s0[r] - m_new); psum += p0[r];
            p1[r] = exp2f(s1[r] - m_new); psum += p1[r];
        }
        psum += __shfl_xor(psum, 16);
        psum += __shfl_xor(psum, 32);
        lsum = lsum * alpha + psum;
        m_run = m_new;

        unsigned int pk0[2], pk1[2];
        pk0[0] = f2bf(p0[0]) | (f2bf(p0[1]) << 16);
        pk0[1] = f2bf(p0[2]) | (f2bf(p0[3]) << 16);
        pk1[0] = f2bf(p1[0]) | (f2bf(p1[1]) << 16);
        pk1[1] = f2bf(p1[2]) | (f2bf(p1[3]) << 16);

        i32x4 pav;
        #pragma unroll
        for (int pp = 0; pp < 4; ++pp) {
            const int src = lo + ((2*g + (pp >> 1)) & 3) * 16;
            const int v0s = __shfl((int)pk0[pp & 1], src, 64);
            const int v1s = __shfl((int)pk1[pp & 1], src, 64);
            pav[pp] = (g < 2) ? v0s : v1s;
        }
        const bf16x8 paf = __builtin_bit_cast(bf16x8, pav);

        float al[4];
        #pragma unroll
        for (int r = 0; r < 4; ++r) al[r] = __shfl(alpha, 4*g + r, 64);
        #pragma unroll
        for (int db = 0; db < 8; ++db) {
            oa[db][0] *= al[0]; oa[db][1] *= al[1];
            oa[db][2] *= al[2]; oa[db][3] *= al[3];
        }

        const char* vl = reinterpret_cast<const char*>(V_lds);
        #pragma unroll
        for (int db = 0; db < 8; ++db) {
            const int slot = g ^ (lo & 3) ^ (db & 3);
            bf16x8 vfr = *reinterpret_cast<const bf16x8*>(vl + db*1024 + lo*64 + slot*16);
            oa[db] = __builtin_amdgcn_mfma_f32_16x16x32_bf16(paf, vfr, oa[db], 0, 0, 0);
        }
    }

    float li[4];
    #pragma unroll
    for (int r = 0; r < 4; ++r) li[r] = 1.0f / __shfl(lsum, 4*g + r, 64);
    #pragma unroll
    for (int db = 0; db < 8; ++db) {
        #pragma unroll
        for (int r = 0; r < 4; ++r) {
            O[(size_t)(q0 + wv*16 + 4*g + r)*QD + h*HD + db*16 + lo] = oa[db][r] * li[r];
        }
    }
}

extern "C" void kernel_launch(void* const* d_in, const int* in_sizes, int n_in,
                              void* d_out, int out_size, void* d_ws, size_t ws_size,
                              hipStream_t stream) {
    const float* q = (const float*)d_in[0];
    const float* k = (const float*)d_in[1];
    const float* v = (const float*)d_in[2];
    float* out = (float*)d_out;
    (void)in_sizes; (void)n_in; (void)out_size;

    if (ws_size >= WS_NEED && d_ws != nullptr) {
        char* kw = (char*)d_ws;
        char* vw = kw + (size_t)NKV * NT_KV * TILE_B;
        conv_k<<<dim3(512), dim3(256), 0, stream>>>(k, kw);
        conv_v<<<dim3(512), dim3(256), 0, stream>>>(v, vw);
        gqa_attn_fwd<<<dim3(64 * NH), dim3(256), 0, stream>>>(q, kw, vw, out);
    } else {
        gqa_attn_fwd_fb<<<dim3((SEQL/64)*NH), dim3(256), 0, stream>>>(q, k, v, out);
    }
}

// Round 17
// 125.842 us; speedup vs baseline: 2.4981x; 1.1584x over previous
//
#include <hip/hip_runtime.h>
#include <hip/hip_bf16.h>

typedef __attribute__((ext_vector_type(8)))  short  bf16x8;
typedef __attribute__((ext_vector_type(4)))  float  f32x4;
typedef __attribute__((ext_vector_type(16))) float  f32x16;
typedef __attribute__((ext_vector_type(4)))  int    i32x4;
typedef __attribute__((ext_vector_type(4)))  unsigned int u32x4;

#define NH   12
#define NKV  2
#define GRP  6
#define HD   128
#define SEQL 4096
#define QD   (NH*HD)
#define KD   (NKV*HD)
#define NT_KV (SEQL/32)     // 128 kv tiles of 32 rows per head
#define TILE_B 8192         // bytes per 32x128 bf16 tile
#define WS_NEED ((size_t)2 * NKV * NT_KV * TILE_B)   // 4 MB: KW + VW

// SCALE * log2(e): softmax in exp2 domain
static constexpr float SCL = 0.08838834764831845f * 1.44269504088896340736f;

static __device__ __forceinline__ unsigned int f2bf(float x) {
    union { __hip_bfloat16 h; unsigned short u; } cv;
    cv.h = __float2bfloat16(x);
    return (unsigned int)cv.u;
}
// packed f32x2 -> bf16x2 (RNE) in ONE instruction (T12 recipe; no builtin)
static __device__ __forceinline__ unsigned int pkcvt(float lo, float hi) {
    unsigned int r;
    asm("v_cvt_pk_bf16_f32 %0, %1, %2" : "=v"(r) : "v"(lo), "v"(hi));
    return r;
}

// ---- pre-pass: K -> bf16 in QK A-fragment order ----
__global__ __launch_bounds__(256) void conv_k(const float* __restrict__ K,
                                              char* __restrict__ KW) {
    int id = blockIdx.x*256 + threadIdx.x;      // 131072 threads
    int l31  = id & 31;
    int hi   = (id >> 5) & 1;
    int c    = (id >> 6) & 7;
    int tile = (id >> 9) & 127;
    int kvh  = id >> 16;
    const float* src = K + (size_t)(tile*32 + l31)*KD + kvh*HD + c*16 + hi*8;
    const f32x4* s4 = reinterpret_cast<const f32x4*>(src);
    f32x4 a = s4[0], b = s4[1];
    bf16x8 t;
    t[0]=(short)f2bf(a[0]); t[1]=(short)f2bf(a[1]); t[2]=(short)f2bf(a[2]); t[3]=(short)f2bf(a[3]);
    t[4]=(short)f2bf(b[0]); t[5]=(short)f2bf(b[1]); t[6]=(short)f2bf(b[2]); t[7]=(short)f2bf(b[3]);
    *reinterpret_cast<bf16x8*>(KW + (size_t)(kvh*NT_KV + tile)*TILE_B
                               + c*1024 + (hi*32 + l31)*16) = t;
}

// ---- pre-pass: V -> bf16 in 32x32x16 MFMA B-fragment layout ----
__global__ __launch_bounds__(256) void conv_v(const float* __restrict__ V,
                                              char* __restrict__ VW) {
    int id = blockIdx.x*256 + threadIdx.x;      // 131072 threads
    int d    = id & 127;
    int hi   = (id >> 7) & 1;
    int kc   = (id >> 8) & 1;
    int tile = (id >> 9) & 127;
    int kvh  = id >> 16;
    const float* vp = V + (size_t)(tile*32 + kc*16 + hi*8)*KD + kvh*HD + d;
    bf16x8 t;
    #pragma unroll
    for (int j = 0; j < 8; ++j) t[j] = (short)f2bf(vp[(size_t)j*KD]);
    char* dst = VW + (size_t)(kvh*NT_KV + tile)*TILE_B
              + (d>>5)*2048 + kc*1024 + (d&31)*32 + hi*16;
    *reinterpret_cast<bf16x8*>(dst) = t;
}

// ===================== fast path =====================
// R16 (uniform pairing + XCD decode) with a register diet targeting
// TOTAL (arch+acc) regs <= 256/wave so 2 waves/SIMD actually co-reside
// (R16 evidence: occupancy ~0.88 waves/SIMD => total was over the 256
// cliff): single-s QK chain (-16 acc regs), V loads issued after QK
// (live-range shrink), cvt_pk asm pack (-~140 VALU/iter, fewer temps).
// NEVER force launch_bounds min-waves (R15: catastrophic spill).
__global__ __launch_bounds__(256) void gqa_attn_fwd(
        const float* __restrict__ Q,
        const char* __restrict__ KW,
        const char* __restrict__ VW,
        float* __restrict__ O)
{
    __shared__ float bufA[32*128];   // 16 KB merge buffer
    __shared__ float bufB[32*128];   // 16 KB merge buffer
    __shared__ float cmA[64];        // m[32], l[32]
    __shared__ float cmB[64];

    const int tid  = threadIdx.x;
    const int wv   = tid >> 6;       // 0..3
    const int lane = tid & 63;
    const int l31  = lane & 31;
    const int hi   = lane >> 5;

    // ---- XCD-aware decode: 768 blocks; xcd=bid&7 -> kvh = xcd>>2 ----
    const int bid = blockIdx.x;
    const int xcd = bid & 7;
    const int i8  = bid >> 3;              // 0..95 (per-XCD block index)
    const int kvh = xcd >> 2;              // XCDs 0-3 -> kvh 0; 4-7 -> kvh 1
    const int j   = (xcd & 3)*96 + i8;     // 0..383 within this kvh
    const int h   = kvh*GRP + (j % GRP);
    const int pr  = j / GRP;               // 0..63 (pair index)

    const char* kw0 = KW + (size_t)kvh*NT_KV*TILE_B;
    const char* vw0 = VW + (size_t)kvh*NT_KV*TILE_B;
    const int klocal = lane*16;
    const int vlocal = l31*32 + hi*16;

    for (int ph = 0; ph < 2; ++ph) {
        const int qt = (ph == 0) ? pr : (127 - pr);
        const int q0 = qt * 32;

        // ---- Q fragments for this phase's q-tile, prescaled ----
        bf16x8 qf[8];
        {
            const float* qp = Q + (size_t)(q0 + l31)*QD + h*HD + hi*8;
            #pragma unroll
            for (int c = 0; c < 8; ++c) {
                const f32x4* p4 = reinterpret_cast<const f32x4*>(qp + c*16);
                f32x4 a = p4[0], b = p4[1];
                bf16x8 f;
                f[0]=(short)f2bf(a[0]*SCL); f[1]=(short)f2bf(a[1]*SCL);
                f[2]=(short)f2bf(a[2]*SCL); f[3]=(short)f2bf(a[3]*SCL);
                f[4]=(short)f2bf(b[0]*SCL); f[5]=(short)f2bf(b[1]*SCL);
                f[6]=(short)f2bf(b[2]*SCL); f[7]=(short)f2bf(b[3]*SCL);
                qf[c] = f;
            }
        }

        f32x16 oa[4];
        #pragma unroll
        for (int dc = 0; dc < 4; ++dc)
            #pragma unroll
            for (int r = 0; r < 16; ++r) oa[dc][r] = 0.f;
        float m_run = -1e30f, lsum = 0.f;   // per-lane HALF-sum (hi splits kv rows)

        // ---- main loop: single K reg buffer, post-QK prefetch ----
        bf16x8 kf[8];
        {
            const char* kt0 = kw0 + (size_t)wv*TILE_B + klocal;
            #pragma unroll
            for (int c = 0; c < 8; ++c)
                kf[c] = *reinterpret_cast<const bf16x8*>(kt0 + c*1024);
        }

        for (int t = wv; t <= qt; t += 4) {
            // ---- QK^T: S^T[kv][q], lane = one q column; single chain ----
            f32x16 s;
            #pragma unroll
            for (int r = 0; r < 16; ++r) s[r] = 0.f;
            __builtin_amdgcn_s_setprio(1);
            #pragma unroll
            for (int c = 0; c < 8; ++c)
                s = __builtin_amdgcn_mfma_f32_32x32x16_bf16(kf[c], qf[c], s, 0, 0, 0);
            __builtin_amdgcn_s_setprio(0);

            // prefetch next K tile into the SAME regs (kf dead after QK issue)
            if (t + 4 <= qt) {
                const char* kt = kw0 + (size_t)(t+4)*TILE_B + klocal;
                #pragma unroll
                for (int c = 0; c < 8; ++c)
                    kf[c] = *reinterpret_cast<const bf16x8*>(kt + c*1024);
            }

            // V loads issued here (after QK), consumed at PV -> latency
            // covered by softmax+pack; vf not live across QK (reg diet)
            const char* vt = vw0 + (size_t)t*TILE_B + vlocal;
            bf16x8 vf[8];
            #pragma unroll
            for (int i = 0; i < 8; ++i)
                vf[i] = *reinterpret_cast<const bf16x8*>(vt + (i>>1)*2048 + (i&1)*1024);

            // ---- causal mask (diagonal tile only) ----
            if (t == qt) {
                const int qabs = q0 + l31;
                #pragma unroll
                for (int r = 0; r < 16; ++r) {
                    const int kvi = q0 + (r&3) + 8*(r>>2) + 4*hi;
                    if (kvi > qabs) s[r] = -1e30f;
                }
            }

            // ---- online softmax (defer-max, THR=8); max tree ----
            float m0 = fmaxf(fmaxf(s[0],s[1]),  fmaxf(s[2],s[3]));
            float m1 = fmaxf(fmaxf(s[4],s[5]),  fmaxf(s[6],s[7]));
            float m2 = fmaxf(fmaxf(s[8],s[9]),  fmaxf(s[10],s[11]));
            float m3 = fmaxf(fmaxf(s[12],s[13]), fmaxf(s[14],s[15]));
            float pmax = fmaxf(fmaxf(m0,m1), fmaxf(m2,m3));
            pmax = fmaxf(pmax, __shfl_xor(pmax, 32));   // halves agree on m

            if (__ballot(pmax > m_run + 8.0f)) {
                const float mnew  = fmaxf(m_run, pmax);
                const float alpha = __builtin_amdgcn_exp2f(m_run - mnew);
                m_run = mnew;
                lsum *= alpha;
                #pragma unroll
                for (int r = 0; r < 16; ++r) {
                    const float ar = __shfl(alpha, (r&3) + 8*(r>>2) + 4*hi, 64);
                    #pragma unroll
                    for (int dc = 0; dc < 4; ++dc) oa[dc][r] *= ar;
                }
            }

            float ps0 = 0.f, ps1 = 0.f;
            #pragma unroll
            for (int r = 0; r < 16; r += 2) {
                s[r]   = __builtin_amdgcn_exp2f(s[r]   - m_run); ps0 += s[r];
                s[r+1] = __builtin_amdgcn_exp2f(s[r+1] - m_run); ps1 += s[r+1];
            }
            lsum += ps0 + ps1;

            // ---- P -> A-fragment: cvt_pk pack + permlane32_swap ----
            unsigned w0, w1, w2, w3, w4, w5, w6, w7;
            {
                unsigned a = pkcvt(s[0],  s[1]),  b = pkcvt(s[4],  s[5]);
                auto r0 = __builtin_amdgcn_permlane32_swap(a, b, false, false);
                w0 = r0[0]; w2 = r0[1];
                unsigned c2 = pkcvt(s[2],  s[3]),  d2 = pkcvt(s[6],  s[7]);
                auto r1 = __builtin_amdgcn_permlane32_swap(c2, d2, false, false);
                w1 = r1[0]; w3 = r1[1];
                unsigned e = pkcvt(s[8],  s[9]),  f = pkcvt(s[12], s[13]);
                auto r2 = __builtin_amdgcn_permlane32_swap(e, f, false, false);
                w4 = r2[0]; w6 = r2[1];
                unsigned g = pkcvt(s[10], s[11]), hh = pkcvt(s[14], s[15]);
                auto r3 = __builtin_amdgcn_permlane32_swap(g, hh, false, false);
                w5 = r3[0]; w7 = r3[1];
            }
            const bf16x8 pa0 = __builtin_bit_cast(bf16x8, (u32x4){w0, w1, w2, w3});
            const bf16x8 pa1 = __builtin_bit_cast(bf16x8, (u32x4){w4, w5, w6, w7});

            // ---- PV ----
            __builtin_amdgcn_s_setprio(1);
            #pragma unroll
            for (int dc = 0; dc < 4; ++dc) {
                oa[dc] = __builtin_amdgcn_mfma_f32_32x32x16_bf16(pa0, vf[dc*2],   oa[dc], 0, 0, 0);
                oa[dc] = __builtin_amdgcn_mfma_f32_32x32x16_bf16(pa1, vf[dc*2+1], oa[dc], 0, 0, 0);
            }
            __builtin_amdgcn_s_setprio(0);
        }

        // ---- combine the two kv-row halves of lsum ----
        lsum += __shfl_xor(lsum, 32);

        // ---- 4-way flash-merge tree for this phase's q-tile ----
        __syncthreads();   // protects buffer reuse across phases
        if (wv == 1) {
            if (hi == 0) { cmA[l31] = m_run; cmA[32 + l31] = lsum; }
            #pragma unroll
            for (int r = 0; r < 16; ++r) {
                const int qr = (r&3) + 8*(r>>2) + 4*hi;
                #pragma unroll
                for (int dc = 0; dc < 4; ++dc) bufA[qr*128 + dc*32 + l31] = oa[dc][r];
            }
        } else if (wv == 3) {
            if (hi == 0) { cmB[l31] = m_run; cmB[32 + l31] = lsum; }
            #pragma unroll
            for (int r = 0; r < 16; ++r) {
                const int qr = (r&3) + 8*(r>>2) + 4*hi;
                #pragma unroll
                for (int dc = 0; dc < 4; ++dc) bufB[qr*128 + dc*32 + l31] = oa[dc][r];
            }
        }
        __syncthreads();
        if (wv == 0 || wv == 2) {
            const float* cb = (wv == 0) ? cmA  : cmB;
            const float* ob = (wv == 0) ? bufA : bufB;
            const float mo = cb[l31], lo2 = cb[32 + l31];
            const float M  = fmaxf(m_run, mo);
            const float a0 = __builtin_amdgcn_exp2f(m_run - M);
            const float a1 = __builtin_amdgcn_exp2f(mo - M);
            lsum  = lsum*a0 + lo2*a1;
            m_run = M;
            #pragma unroll
            for (int r = 0; r < 16; ++r) {
                const int qr = (r&3) + 8*(r>>2) + 4*hi;
                const float a0r = __shfl(a0, qr, 64);
                const float a1r = __shfl(a1, qr, 64);
                #pragma unroll
                for (int dc = 0; dc < 4; ++dc)
                    oa[dc][r] = oa[dc][r]*a0r + ob[qr*128 + dc*32 + l31]*a1r;
            }
        }
        __syncthreads();   // w0 done reading bufA before w2 overwrites it
        if (wv == 2) {
            if (hi == 0) { cmA[l31] = m_run; cmA[32 + l31] = lsum; }
            #pragma unroll
            for (int r = 0; r < 16; ++r) {
                const int qr = (r&3) + 8*(r>>2) + 4*hi;
                #pragma unroll
                for (int dc = 0; dc < 4; ++dc) bufA[qr*128 + dc*32 + l31] = oa[dc][r];
            }
        }
        __syncthreads();
        if (wv == 0) {
            const float mo = cmA[l31], lo2 = cmA[32 + l31];
            const float M  = fmaxf(m_run, mo);
            const float a0 = __builtin_amdgcn_exp2f(m_run - M);
            const float a1 = __builtin_amdgcn_exp2f(mo - M);
            const float inv = 1.0f / (lsum*a0 + lo2*a1);
            #pragma unroll
            for (int r = 0; r < 16; ++r) {
                const int qr = (r&3) + 8*(r>>2) + 4*hi;
                const float a0r = __shfl(a0, qr, 64);
                const float a1r = __shfl(a1, qr, 64);
                const float ivr = __shfl(inv, qr, 64);
                float* op = O + (size_t)(q0 + qr)*QD + h*HD + l31;
                #pragma unroll
                for (int dc = 0; dc < 4; ++dc) {
                    const float merged = oa[dc][r]*a0r + bufA[qr*128 + dc*32 + l31]*a1r;
                    op[dc*32] = merged * ivr;
                }
            }
        }
    }
}

// ===================== fallback: self-staging (no workspace), verified R1 =====================
__global__ __launch_bounds__(256) void gqa_attn_fwd_fb(
        const float* __restrict__ Q, const float* __restrict__ K,
        const float* __restrict__ V, float* __restrict__ O)
{
    __shared__ unsigned short K_lds[32*128];
    __shared__ unsigned short V_lds[32*128];

    const int tid  = threadIdx.x;
    const int wv   = tid >> 6;
    const int lane = tid & 63;
    const int lo   = lane & 15;
    const int g    = lane >> 4;

    const int bid = blockIdx.x;
    const int h   = bid % NH;
    const int qt  = (SEQL/64 - 1) - bid / NH;
    const int q0  = qt * 64;
    const int kvh = h / GRP;

    bf16x8 qf[4];
    {
        const int qrow = q0 + wv*16 + lo;
        const float* qp = Q + (size_t)qrow*QD + h*HD + g*8;
        #pragma unroll
        for (int c = 0; c < 4; ++c) {
            const f32x4* p = reinterpret_cast<const f32x4*>(qp + c*32);
            f32x4 a = p[0], b = p[1];
            bf16x8 f;
            f[0]=(short)f2bf(a[0]*SCL); f[1]=(short)f2bf(a[1]*SCL);
            f[2]=(short)f2bf(a[2]*SCL); f[3]=(short)f2bf(a[3]*SCL);
            f[4]=(short)f2bf(b[0]*SCL); f[5]=(short)f2bf(b[1]*SCL);
            f[6]=(short)f2bf(b[2]*SCL); f[7]=(short)f2bf(b[3]*SCL);
            qf[c] = f;
        }
    }

    f32x4 oa[8];
    #pragma unroll
    for (int i = 0; i < 8; ++i) oa[i] = (f32x4){0.f, 0.f, 0.f, 0.f};
    float m_run = -1e30f, lsum = 0.f;

    const int qmax_w = q0 + wv*16 + 15;
    const int nt = q0/32 + 2;

    for (int t = 0; t < nt; ++t) {
        const int kvb = t*32;
        __syncthreads();
        {
            const int row = tid >> 3;
            const int dc  = (tid & 7) * 16;
            const float* kp = K + (size_t)(kvb+row)*KD + kvh*HD + dc;
            const f32x4* kp4 = reinterpret_cast<const f32x4*>(kp);
            f32x4 a0 = kp4[0], a1 = kp4[1], a2 = kp4[2], a3 = kp4[3];
            bf16x8 t0, t1;
            t0[0]=(short)f2bf(a0[0]); t0[1]=(short)f2bf(a0[1]); t0[2]=(short)f2bf(a0[2]); t0[3]=(short)f2bf(a0[3]);
            t0[4]=(short)f2bf(a1[0]); t0[5]=(short)f2bf(a1[1]); t0[6]=(short)f2bf(a1[2]); t0[7]=(short)f2bf(a1[3]);
            t1[0]=(short)f2bf(a2[0]); t1[1]=(short)f2bf(a2[1]); t1[2]=(short)f2bf(a2[2]); t1[3]=(short)f2bf(a2[3]);
            t1[4]=(short)f2bf(a3[0]); t1[5]=(short)f2bf(a3[1]); t1[6]=(short)f2bf(a3[2]); t1[7]=(short)f2bf(a3[3]);
            char* kl = reinterpret_cast<char*>(K_lds);
            const int byte = row*256 + dc*2;
            const int swzw = (row & 7) << 4;
            *reinterpret_cast<bf16x8*>(kl + ((byte)      ^ swzw)) = t0;
            *reinterpret_cast<bf16x8*>(kl + ((byte + 16) ^ swzw)) = t1;
        }
        {
            const int kv0   = (tid >> 4) * 2;
            const int dbase = (tid & 15) * 8;
            const float* vp = V + (size_t)(kvb+kv0)*KD + kvh*HD + dbase;
            const f32x4* v0 = reinterpret_cast<const f32x4*>(vp);
            const f32x4* v1 = reinterpret_cast<const f32x4*>(vp + KD);
            f32x4 a0 = v0[0], a1 = v0[1], b0 = v1[0], b1 = v1[1];
            unsigned int* vf = reinterpret_cast<unsigned int*>(V_lds);
            #pragma unroll
            for (int i = 0; i < 8; ++i) {
                float x0 = (i < 4) ? a0[i] : a1[i-4];
                float x1 = (i < 4) ? b0[i] : b1[i-4];
                unsigned int pkv = f2bf(x0) | (f2bf(x1) << 16);
                const int d  = dbase + i;
                const int db = d >> 4, dl = d & 15;
                const int slot = (kv0 >> 3) ^ (d & 3) ^ (db & 3);
                const int byte = db*1024 + dl*64 + slot*16 + (kv0 & 7)*2;
                vf[byte >> 2] = pkv;
            }
        }
        __syncthreads();

        if (kvb > qmax_w) continue;

        f32x4 s0 = {0,0,0,0}, s1 = {0,0,0,0};
        {
            const char* kl = reinterpret_cast<const char*>(K_lds);
            const int r0 = lo, r1 = lo + 16;
            const int sw0 = (r0 & 7) << 4, sw1 = (r1 & 7) << 4;
            #pragma unroll
            for (int c = 0; c < 4; ++c) {
                bf16x8 ka = *reinterpret_cast<const bf16x8*>(kl + ((r0*256 + c*64 + g*16) ^ sw0));
                bf16x8 kb = *reinterpret_cast<const bf16x8*>(kl + ((r1*256 + c*64 + g*16) ^ sw1));
                s0 = __builtin_amdgcn_mfma_f32_16x16x32_bf16(ka, qf[c], s0, 0, 0, 0);
                s1 = __builtin_amdgcn_mfma_f32_16x16x32_bf16(kb, qf[c], s1, 0, 0, 0);
            }
        }

        const int qabs = q0 + wv*16 + lo;
        if (kvb + 31 > q0 + wv*16) {
            #pragma unroll
            for (int r = 0; r < 4; ++r) {
                if (kvb + 4*g + r      > qabs) s0[r] = -1e30f;
                if (kvb + 16 + 4*g + r > qabs) s1[r] = -1e30f;
            }
        }

        float pmax = fmaxf(fmaxf(fmaxf(s0[0],s0[1]), fmaxf(s0[2],s0[3])),
                           fmaxf(fmaxf(s1[0],s1[1]), fmaxf(s1[2],s1[3])));
        pmax = fmaxf(pmax, __shfl_xor(pmax, 16));
        pmax = fmaxf(pmax, __shfl_xor(pmax, 32));
        const float m_new = fmaxf(m_run, pmax);
        const float alpha = exp2f(m_run - m_new);
        float p0[4], p1[4];
        float psum = 0.f;
        #pragma unroll
        for (int r = 0; r < 4; ++r) {
            p0[r] = exp2f(s0[r] - m_new); psum += p0[r];
            p1[r] = exp2f(s1[r] - m_new); psum += p1[r];
        }
        psum += __shfl_xor(psum, 16);
        psum += __shfl_xor(psum, 32);
        lsum = lsum * alpha + psum;
        m_run = m_new;

        unsigned int pk0[2], pk1[2];
        pk0[0] = f2bf(p0[0]) | (f2bf(p0[1]) << 16);
        pk0[1] = f2bf(p0[2]) | (f2bf(p0[3]) << 16);
        pk1[0] = f2bf(p1[0]) | (f2bf(p1[1]) << 16);
        pk1[1] = f2bf(p1[2]) | (f2bf(p1[3]) << 16);

        i32x4 pav;
        #pragma unroll
        for (int pp = 0; pp < 4; ++pp) {
            const int src = lo + ((2*g + (pp >> 1)) & 3) * 16;
            const int v0s = __shfl((int)pk0[pp & 1], src, 64);
            const int v1s = __shfl((int)pk1[pp & 1], src, 64);
            pav[pp] = (g < 2) ? v0s : v1s;
        }
        const bf16x8 paf = __builtin_bit_cast(bf16x8, pav);

        float al[4];
        #pragma unroll
        for (int r = 0; r < 4; ++r) al[r] = __shfl(alpha, 4*g + r, 64);
        #pragma unroll
        for (int db = 0; db < 8; ++db) {
            oa[db][0] *= al[0]; oa[db][1] *= al[1];
            oa[db][2] *= al[2]; oa[db][3] *= al[3];
        }

        const char* vl = reinterpret_cast<const char*>(V_lds);
        #pragma unroll
        for (int db = 0; db < 8; ++db) {
            const int slot = g ^ (lo & 3) ^ (db & 3);
            bf16x8 vfr = *reinterpret_cast<const bf16x8*>(vl + db*1024 + lo*64 + slot*16);
            oa[db] = __builtin_amdgcn_mfma_f32_16x16x32_bf16(paf, vfr, oa[db], 0, 0, 0);
        }
    }

    float li[4];
    #pragma unroll
    for (int r = 0; r < 4; ++r) li[r] = 1.0f / __shfl(lsum, 4*g + r, 64);
    #pragma unroll
    for (int db = 0; db < 8; ++db) {
        #pragma unroll
        for (int r = 0; r < 4; ++r) {
            O[(size_t)(q0 + wv*16 + 4*g + r)*QD + h*HD + db*16 + lo] = oa[db][r] * li[r];
        }
    }
}

extern "C" void kernel_launch(void* const* d_in, const int* in_sizes, int n_in,
                              void* d_out, int out_size, void* d_ws, size_t ws_size,
                              hipStream_t stream) {
    const float* q = (const float*)d_in[0];
    const float* k = (const float*)d_in[1];
    const float* v = (const float*)d_in[2];
    float* out = (float*)d_out;
    (void)in_sizes; (void)n_in; (void)out_size;

    if (ws_size >= WS_NEED && d_ws != nullptr) {
        char* kw = (char*)d_ws;
        char* vw = kw + (size_t)NKV * NT_KV * TILE_B;
        conv_k<<<dim3(512), dim3(256), 0, stream>>>(k, kw);
        conv_v<<<dim3(512), dim3(256), 0, stream>>>(v, vw);
        gqa_attn_fwd<<<dim3(64 * NH), dim3(256), 0, stream>>>(q, kw, vw, out);
    } else {
        gqa_attn_fwd_fb<<<dim3((SEQL/64)*NH), dim3(256), 0, stream>>>(q, k, v, out);
    }
}